// Round 14
// baseline (196.177 us; speedup 1.0000x reference)
//
#include <hip/hip_runtime.h>
#include <math.h>

#define NN 256
#define HH 8
#define DD 64
#define BH 16
#define SCALER 0.125f

#define REG     (BH*NN*DD)             // 262144 floats
#define MAT_SZ  (BH*NN*NN)             // 1048576 floats
// fp16 buffers overlay the dead a/b/c projections (only v1,v2 at 3*REG,4*REG live on)
#define OFF_XH  0                      // fp16 [bh][i][j]
#define OFF_V1T 524288                 // fp16 [bh][d][j]
#define OFF_QKV 0
#define OFF_X   1310720
#define OFF_Y   (OFF_X + MAT_SZ)
#define OFF_Z   (OFF_Y + MAT_SZ)
#define OFF_MX  (OFF_Z + MAT_SZ)       // 4096
#define OFF_MY  (OFF_MX + BH*NN)       // 16
#define OFF_MZ  (OFF_MY + 16)          // 4096
#define OFF_YT  4464656                // fp16 [bh][k][j]
#define OFF_V2T 4988944                // fp32 [bh][d][k]
#define KB      4
#define OFF_UP  5251088                // fp32 [kb][bh][i][d]
#define OFF_DN  6299664                // fp32 [kb][bh][i]  (16384)
#define OFF_YR  6316048                // fp32 yrow[4096]
// end 6320144 floats = 25.3 MB

typedef _Float16 f16x8 __attribute__((ext_vector_type(8)));
typedef _Float16 f16x4 __attribute__((ext_vector_type(4)));
typedef float    f32x4 __attribute__((ext_vector_type(4)));

// ---------------- K1: projection GEMM (unchanged, validated) ----------------
__global__ __launch_bounds__(256) void k_proj(const float* __restrict__ Hs,
                                              const float* __restrict__ W,
                                              float* __restrict__ qkv) {
  __shared__ float As[16][68];
  __shared__ float Bs[16][68];
  const int bx = blockIdx.x, by = blockIdx.y;
  const int tid = threadIdx.x;
  const int ri = tid >> 4, ci = tid & 15;
  const int o0 = bx * 64, m0 = by * 64;
  float acc[4][4] = {};
  for (int k0 = 0; k0 < 512; k0 += 16) {
    __syncthreads();
    {
      const int m = tid >> 2, kq = (tid & 3) * 4;
      float4 va = *(const float4*)&Hs[(m0 + m) * 512 + k0 + kq];
      As[kq + 0][m] = va.x; As[kq + 1][m] = va.y; As[kq + 2][m] = va.z; As[kq + 3][m] = va.w;
      float4 vb = *(const float4*)&W[(o0 + m) * 512 + k0 + kq];
      Bs[kq + 0][m] = vb.x; Bs[kq + 1][m] = vb.y; Bs[kq + 2][m] = vb.z; Bs[kq + 3][m] = vb.w;
    }
    __syncthreads();
#pragma unroll
    for (int kk = 0; kk < 16; ++kk) {
      float4 a = *(const float4*)&As[kk][ri * 4];
      float4 b = *(const float4*)&Bs[kk][ci * 4];
      acc[0][0] += a.x * b.x; acc[0][1] += a.x * b.y; acc[0][2] += a.x * b.z; acc[0][3] += a.x * b.w;
      acc[1][0] += a.y * b.x; acc[1][1] += a.y * b.y; acc[1][2] += a.y * b.z; acc[1][3] += a.y * b.w;
      acc[2][0] += a.z * b.x; acc[2][1] += a.z * b.y; acc[2][2] += a.z * b.z; acc[2][3] += a.z * b.w;
      acc[3][0] += a.w * b.x; acc[3][1] += a.w * b.y; acc[3][2] += a.w * b.z; acc[3][3] += a.w * b.w;
    }
  }
  const int p = o0 >> 9;
  const int h = (o0 >> 6) & 7;
  const int d0 = ci * 4;
#pragma unroll
  for (int l = 0; l < 4; ++l) {
    const int r = m0 + ri * 4 + l;
    const int b = r >> 8, n = r & 255;
    float* dst = qkv + p * REG + (b * 8 + h) * (NN * DD) + n * DD + d0;
    *(float4*)dst = make_float4(acc[l][0], acc[l][1], acc[l][2], acc[l][3]);
  }
}

// ---------------- K2: score matrices (unchanged, validated) ----------------
__global__ __launch_bounds__(256) void k_scores(const float* __restrict__ qkv,
                                                float* __restrict__ ws) {
  __shared__ float Us[32][68];
  __shared__ float Ws_[32][68];
  const int ms = blockIdx.z, bh = blockIdx.y;
  const int tr = blockIdx.x >> 3, tc = blockIdx.x & 7;
  const float* U; const float* Wm; float* O;
  if (ms == 0)      { U = qkv + 0 * REG; Wm = qkv + 1 * REG; O = ws + OFF_X; }
  else if (ms == 1) { U = qkv + 1 * REG; Wm = qkv + 2 * REG; O = ws + OFF_Y; }
  else              { U = qkv + 2 * REG; Wm = qkv + 0 * REG; O = ws + OFF_Z; }
  U  += bh * (NN * DD);
  Wm += bh * (NN * DD);
  O  += bh * (NN * NN);
  const int i0 = tr * 32, k0 = tc * 32;
  const int tid = threadIdx.x;
  {
    const int r = tid >> 3, d8 = (tid & 7) * 8;
    *(float4*)&Us[r][d8]      = *(const float4*)&U[(i0 + r) * DD + d8];
    *(float4*)&Us[r][d8 + 4]  = *(const float4*)&U[(i0 + r) * DD + d8 + 4];
    *(float4*)&Ws_[r][d8]     = *(const float4*)&Wm[(k0 + r) * DD + d8];
    *(float4*)&Ws_[r][d8 + 4] = *(const float4*)&Wm[(k0 + r) * DD + d8 + 4];
  }
  __syncthreads();
  const int ri = tid >> 4, ci = tid & 15;
  float a00 = 0.f, a01 = 0.f, a10 = 0.f, a11 = 0.f;
#pragma unroll
  for (int dd = 0; dd < 16; ++dd) {
    float4 u0 = *(const float4*)&Us[ri][dd * 4];
    float4 u1 = *(const float4*)&Us[ri + 16][dd * 4];
    float4 w0 = *(const float4*)&Ws_[ci][dd * 4];
    float4 w1 = *(const float4*)&Ws_[ci + 16][dd * 4];
    a00 += u0.x * w0.x + u0.y * w0.y + u0.z * w0.z + u0.w * w0.w;
    a01 += u0.x * w1.x + u0.y * w1.y + u0.z * w1.z + u0.w * w1.w;
    a10 += u1.x * w0.x + u1.y * w0.y + u1.z * w0.z + u1.w * w0.w;
    a11 += u1.x * w1.x + u1.y * w1.y + u1.z * w1.z + u1.w * w1.w;
  }
#define STORE_SC(accv, rr, cc) { \
    int row = (rr), col = (cc); \
    O[row * NN + col] = (accv) * SCALER + fminf((float)(col - row), 0.f); }
  STORE_SC(a00, i0 + ri,      k0 + ci)
  STORE_SC(a01, i0 + ri,      k0 + ci + 16)
  STORE_SC(a10, i0 + ri + 16, k0 + ci)
  STORE_SC(a11, i0 + ri + 16, k0 + ci + 16)
#undef STORE_SC
}

// ---------------- K3: all max reductions in one kernel ----------------
__global__ __launch_bounds__(256) void k_maxes(const float* __restrict__ ws,
                                               float* __restrict__ mx,
                                               float* __restrict__ yrow,
                                               float* __restrict__ mz) {
  const int blk = blockIdx.x, tid = threadIdx.x;
  if (blk < 2048) {
    const int wid = tid >> 6, lane = tid & 63;
    const float* base = ws + (blk < 1024 ? OFF_X : OFF_Y);
    float* out = (blk < 1024) ? mx : yrow;
    const int gr = (blk & 1023) * 4 + wid;
    float4 v = *(const float4*)&base[gr * 256 + lane * 4];
    float m = fmaxf(fmaxf(v.x, v.y), fmaxf(v.z, v.w));
#pragma unroll
    for (int off = 32; off; off >>= 1) m = fmaxf(m, __shfl_xor(m, off));
    if (lane == 0) out[gr] = m;
  } else {
    const int b2 = blk - 2048;            // 0..63
    const int bh = b2 >> 2, ic = b2 & 3;
    const int il = tid & 63, kp = tid >> 6;
    const int i = ic * 64 + il;
    const float* Zb = ws + OFF_Z;
    float m = -3.4e38f;
    for (int k = kp; k < 256; k += 4) m = fmaxf(m, Zb[bh * (NN * NN) + k * NN + i]);
    __shared__ float red[4][64];
    red[kp][il] = m;
    __syncthreads();
    if (kp == 0)
      mz[bh * NN + i] = fmaxf(fmaxf(red[0][il], red[1][il]), fmaxf(red[2][il], red[3][il]));
  }
}

// ---------------- K3b: reduce yrow (4096) -> my[16] ----------------
__global__ __launch_bounds__(256) void k_ymax2(const float* __restrict__ yrow, float* __restrict__ my) {
  const int bh = blockIdx.x, tid = threadIdx.x;
  float m = yrow[bh * 256 + tid];
#pragma unroll
  for (int off = 32; off; off >>= 1) m = fmaxf(m, __shfl_xor(m, off));
  __shared__ float red[4];
  if ((tid & 63) == 0) red[tid >> 6] = m;
  __syncthreads();
  if (tid == 0) my[bh] = fmaxf(fmaxf(red[0], red[1]), fmaxf(red[2], red[3]));
}

// ---------------- K4: fused exp + convert + transpose (unchanged) ----------------
__global__ __launch_bounds__(256) void k_cvtexp(float* __restrict__ ws) {
  __shared__ float T[64][65];
  const int blk = blockIdx.x, tid = threadIdx.x;
  if (blk < 256) {
    const float* X = ws + OFF_X;
    _Float16* Xh = (_Float16*)(ws + OFF_XH);
    const int gt = blk * 256 + tid;
    const int base = gt * 16;
    const float s = ws[OFF_MX + (gt >> 4)];
#pragma unroll
    for (int q = 0; q < 4; ++q) {
      float4 v = *(const float4*)&X[base + q * 4];
      f16x4 o = {(_Float16)expf(v.x - s), (_Float16)expf(v.y - s),
                 (_Float16)expf(v.z - s), (_Float16)expf(v.w - s)};
      *(f16x4*)&Xh[base + q * 4] = o;
    }
  } else if (blk < 512) {
    const int b2 = blk - 256;
    const int bh = b2 >> 4, jt = (b2 >> 2) & 3, kt = b2 & 3;
    const float* Y = ws + OFF_Y + bh * 65536;
    _Float16* Yt = (_Float16*)(ws + OFF_YT) + bh * 65536;
    const float s = ws[OFF_MY + bh];
    const int j0 = jt * 64, k0 = kt * 64;
#pragma unroll 4
    for (int p = 0; p < 16; ++p) {
      const int idx = p * 256 + tid, r = idx >> 6, c = idx & 63;
      T[r][c] = Y[(j0 + r) * 256 + k0 + c];
    }
    __syncthreads();
#pragma unroll 4
    for (int p = 0; p < 16; ++p) {
      const int idx = p * 256 + tid, r = idx >> 6, c = idx & 63;
      Yt[(k0 + r) * 256 + j0 + c] = (_Float16)expf(T[c][r] - s);
    }
  } else if (blk < 576) {
    const int b2 = blk - 512;
    const int bh = b2 >> 2, jt = b2 & 3;
    const float* v1 = ws + OFF_QKV + 3 * REG + bh * 16384;
    _Float16* v1t = (_Float16*)(ws + OFF_V1T) + bh * 16384;
    const int j0 = jt * 64;
#pragma unroll 4
    for (int p = 0; p < 16; ++p) {
      const int idx = p * 256 + tid, r = idx >> 6, c = idx & 63;
      T[r][c] = v1[(j0 + r) * 64 + c];
    }
    __syncthreads();
#pragma unroll 4
    for (int p = 0; p < 16; ++p) {
      const int idx = p * 256 + tid, r = idx >> 6, c = idx & 63;
      v1t[r * 256 + j0 + c] = (_Float16)T[c][r];
    }
  } else if (blk < 640) {
    const int b2 = blk - 576;
    const int bh = b2 >> 2, kt = b2 & 3;
    const float* v2 = ws + OFF_QKV + 4 * REG + bh * 16384;
    float* v2t = ws + OFF_V2T + bh * 16384;
    const int k0 = kt * 64;
#pragma unroll 4
    for (int p = 0; p < 16; ++p) {
      const int idx = p * 256 + tid, r = idx >> 6, c = idx & 63;
      T[r][c] = v2[(k0 + r) * 64 + c];
    }
    __syncthreads();
#pragma unroll 4
    for (int p = 0; p < 16; ++p) {
      const int idx = p * 256 + tid, r = idx >> 6, c = idx & 63;
      v2t[r * 256 + k0 + c] = T[c][r];
    }
  } else {
    const int rem = (blk - 640) * 256 + tid;
    const int bh = rem >> 14, rr = rem & 16383;
    const int c4 = (rr & 63) * 4;
    float4* base = (float4*)(ws + OFF_Z);
    float4 v = base[rem];
    float4 s = *(const float4*)&ws[OFF_MZ + bh * NN + c4];
    v.x = expf(v.x - s.x); v.y = expf(v.y - s.y); v.z = expf(v.z - s.z); v.w = expf(v.w - s.w);
    base[rem] = v;
  }
}

// ---------------- K5: MFMA triple contraction, v5: 4-i-tile waves ----------------
// r12 falsified the spill theory (VGPR stayed 80 under a 256 cap; fragments live
// in AGPRs). New model: LDS-read-instruction + VALU issue bound (~1.05M
// ds_read_b128 ~= 17us > 16.6us MFMA floor). v5 halves both: each wave owns all
// 4 i-tiles (Xf[4][8]) so one vf read feeds 4 MFMA (was 2); freed wave bit
// splits d (dsub): waves = 4 k16 x 2 dsub. Same grid, same LDS, same epilogue.
__global__ __launch_bounds__(512, 2) void k_heavy(const float* __restrict__ ws,
                                                  float* __restrict__ upP,
                                                  float* __restrict__ dnP) {
  const int kb = blockIdx.x, ib = blockIdx.y, zz = blockIdx.z;
  const int bh = zz >> 2, dp = zz & 3;
  const int k0 = kb * 64, i0 = ib * 64, d0 = dp * 16;
  const int tid = threadIdx.x;
  const int w = tid >> 6, lane = tid & 63;
  const int k16 = w & 3, dsub = w >> 2;   // dsub in {0,1}: which 8 d-slots
  const int li = lane & 15, grp = lane >> 4;

  __shared__ _Float16 v1s[16 * 256];   // 8 KB
  __shared__ float v2s[16 * 64];       // 4 KB
  __shared__ float up_l[4][64][20];    // 20.5 KB
  __shared__ float dn_l[4][64];        // 1 KB

  const _Float16* Xh  = (const _Float16*)(ws + OFF_XH);
  const _Float16* Yt  = (const _Float16*)(ws + OFF_YT);
  const _Float16* v1t = (const _Float16*)(ws + OFF_V1T);
  const float*    v2t = ws + OFF_V2T;
  const float*    Zp  = ws + OFF_Z + bh * 65536;

  {
    const float4* src = (const float4*)(v1t + bh * 16384 + d0 * 256);
    ((float4*)v1s)[tid] = src[tid];
  }
  if (tid < 256) {
    const int d = tid >> 4, kq = (tid & 15) * 4;
    *(float4*)&v2s[d * 64 + kq] = *(const float4*)&v2t[bh * 16384 + (d0 + d) * 256 + k0 + kq];
  }

  // fragments (d-independent): Yf 8, Xf 4 i-tiles x 8 js
  f16x8 Yf[8];
  {
    const _Float16* yb = Yt + (long)bh * 65536 + (k0 + k16 * 16 + li) * 256 + grp * 8;
#pragma unroll
    for (int js = 0; js < 8; ++js) Yf[js] = *(const f16x8*)(yb + js * 32);
  }
  f16x8 Xf[4][8];
#pragma unroll
  for (int iq = 0; iq < 4; ++iq) {
    const _Float16* xb = Xh + (long)bh * 65536 + (i0 + iq * 16 + li) * 256 + grp * 8;
#pragma unroll
    for (int js = 0; js < 8; ++js) Xf[iq][js] = *(const f16x8*)(xb + js * 32);
  }
  float Zr[4][4];
#pragma unroll
  for (int iq = 0; iq < 4; ++iq)
#pragma unroll
    for (int r = 0; r < 4; ++r)
      Zr[iq][r] = Zp[(k0 + k16 * 16 + grp * 4 + r) * 256 + i0 + iq * 16 + li];

  __syncthreads();

  for (int dd = 0; dd < 8; ++dd) {
    const int dloc = dsub * 8 + dd;
    f32x4 acc0 = {0.f,0.f,0.f,0.f}, acc1 = {0.f,0.f,0.f,0.f};
    f32x4 acc2 = {0.f,0.f,0.f,0.f}, acc3 = {0.f,0.f,0.f,0.f};
#pragma unroll
    for (int js = 0; js < 8; ++js) {
      f16x8 vf = *(const f16x8*)&v1s[dloc * 256 + js * 32 + grp * 8];
      f16x8 ad = Yf[js] * vf;                 // A_d = Y ∘ v1_d
      acc0 = __builtin_amdgcn_mfma_f32_16x16x32_f16(ad, Xf[0][js], acc0, 0, 0, 0);
      acc1 = __builtin_amdgcn_mfma_f32_16x16x32_f16(ad, Xf[1][js], acc1, 0, 0, 0);
      acc2 = __builtin_amdgcn_mfma_f32_16x16x32_f16(ad, Xf[2][js], acc2, 0, 0, 0);
      acc3 = __builtin_amdgcn_mfma_f32_16x16x32_f16(ad, Xf[3][js], acc3, 0, 0, 0);
    }
    f32x4 w2 = *(const f32x4*)&v2s[dloc * 64 + k16 * 16 + grp * 4];
#define EPI(accv, iq) { \
      float s = (accv[0] * Zr[iq][0]) * w2[0] + (accv[1] * Zr[iq][1]) * w2[1] \
              + (accv[2] * Zr[iq][2]) * w2[2] + (accv[3] * Zr[iq][3]) * w2[3]; \
      s += __shfl_xor(s, 16); s += __shfl_xor(s, 32); \
      if (lane < 16) up_l[k16][iq * 16 + li][dloc] = s; }
    EPI(acc0, 0) EPI(acc1, 1) EPI(acc2, 2) EPI(acc3, 3)
#undef EPI
  }
  if (dp == 3 && dsub == 1) { // down slot: A = Y (v1 == 1), v2 == 1
    f32x4 acc0 = {0.f,0.f,0.f,0.f}, acc1 = {0.f,0.f,0.f,0.f};
    f32x4 acc2 = {0.f,0.f,0.f,0.f}, acc3 = {0.f,0.f,0.f,0.f};
#pragma unroll
    for (int js = 0; js < 8; ++js) {
      acc0 = __builtin_amdgcn_mfma_f32_16x16x32_f16(Yf[js], Xf[0][js], acc0, 0, 0, 0);
      acc1 = __builtin_amdgcn_mfma_f32_16x16x32_f16(Yf[js], Xf[1][js], acc1, 0, 0, 0);
      acc2 = __builtin_amdgcn_mfma_f32_16x16x32_f16(Yf[js], Xf[2][js], acc2, 0, 0, 0);
      acc3 = __builtin_amdgcn_mfma_f32_16x16x32_f16(Yf[js], Xf[3][js], acc3, 0, 0, 0);
    }
#define EPID(accv, iq) { \
      float s = accv[0] * Zr[iq][0] + accv[1] * Zr[iq][1] \
              + accv[2] * Zr[iq][2] + accv[3] * Zr[iq][3]; \
      s += __shfl_xor(s, 16); s += __shfl_xor(s, 32); \
      if (lane < 16) dn_l[k16][iq * 16 + li] = s; }
    EPID(acc0, 0) EPID(acc1, 1) EPID(acc2, 2) EPID(acc3, 3)
#undef EPID
  }
  __syncthreads();
  // writeout: sum the 4 k16 partials (unchanged)
  {
    const int il = tid >> 3, dq = (tid & 7) * 2;
    float a = up_l[0][il][dq]     + up_l[1][il][dq]     + up_l[2][il][dq]     + up_l[3][il][dq];
    float b = up_l[0][il][dq + 1] + up_l[1][il][dq + 1] + up_l[2][il][dq + 1] + up_l[3][il][dq + 1];
    float* dst = upP + ((long)((kb * 16 + bh) * 256) + i0 + il) * 64 + d0 + dq;
    dst[0] = a; dst[1] = b;
  }
  if (dp == 3 && tid < 64)
    dnP[(kb * 16 + bh) * 256 + i0 + tid] =
        dn_l[0][tid] + dn_l[1][tid] + dn_l[2][tid] + dn_l[3][tid];
}

// ---------------- K6: combine 4 k-partials, divide, write [b][n][h*64+d] ----------------
__global__ __launch_bounds__(256) void k_final(const float* __restrict__ ws_in, float* __restrict__ out) {
  const int g = blockIdx.x * 256 + threadIdx.x;
  const int e0 = g * 4;
  const int c = e0 & 511, n = (e0 >> 9) & 255, b = e0 >> 17;
  const int h = c >> 6, d = c & 63;
  const int bh = b * 8 + h;
  const float* upP = ws_in + OFF_UP;
  const float* dnP = ws_in + OFF_DN;
  float4 acc = make_float4(0.f, 0.f, 0.f, 0.f);
  float dn = 0.f;
#pragma unroll
  for (int ks = 0; ks < KB; ++ks) {
    const float4 u = *(const float4*)&upP[((ks * 16 + bh) * 256 + n) * 64 + d];
    acc.x += u.x; acc.y += u.y; acc.z += u.z; acc.w += u.w;
    dn += dnP[(ks * 16 + bh) * 256 + n];
  }
  const float inv = 1.f / (dn + 1e-9f);
  acc.x *= inv; acc.y *= inv; acc.z *= inv; acc.w *= inv;
  *(float4*)&out[e0] = acc;
}

extern "C" void kernel_launch(void* const* d_in, const int* in_sizes, int n_in,
                              void* d_out, int out_size, void* d_ws, size_t ws_size,
                              hipStream_t stream) {
  (void)in_sizes; (void)n_in; (void)out_size; (void)ws_size;
  const float* hidden = (const float*)d_in[0];
  const float* W      = (const float*)d_in[1];
  float* ws  = (float*)d_ws;
  float* out = (float*)d_out;

  k_proj<<<dim3(40, 8), 256, 0, stream>>>(hidden, W, ws + OFF_QKV);
  k_scores<<<dim3(64, BH, 3), 256, 0, stream>>>(ws + OFF_QKV, ws);
  k_maxes<<<dim3(2112), 256, 0, stream>>>(ws, ws + OFF_MX, ws + OFF_YR, ws + OFF_MZ);
  k_ymax2<<<dim3(16), 256, 0, stream>>>(ws + OFF_YR, ws + OFF_MY);
  k_cvtexp<<<dim3(1664), 256, 0, stream>>>(ws);
  k_heavy<<<dim3(KB, 4, 64), 512, 0, stream>>>(ws, ws + OFF_UP, ws + OFF_DN);
  k_final<<<dim3(256), 256, 0, stream>>>(ws, out);
}